// Round 4
// baseline (629.119 us; speedup 1.0000x reference)
//
#include <hip/hip_runtime.h>

// RNN scan: T=750 sequential steps, x[B=1024,H=100].
//   r = tanh(x); x += ALPHA*(-x + r@J^T + u@b_in^T + c_x + 0.1*n)
// Structure: 1 batch element per block, 128 threads (2 waves), 1024 blocks
// -> 4 independent blocks per CU. Barriers sync only 2 waves; the other 3
// blocks on the CU keep issuing -> per-step serial tail overlaps.
// Thread tid owns h=tid (tid<100). J row in registers (50 v2f, pinned),
// k-packed v_pk_fma_f32, r broadcast via double-buffered LDS.

typedef float v2f __attribute__((ext_vector_type(2)));

#define TSTEPS 750
#define BATCH  1024
#define HID    100
#define THREADS 128

constexpr float ALPHA = 0.1f;   // DT/TAU
constexpr float NSTD  = 0.1f;

__device__ __forceinline__ float ftanh(float x) {
    // tanh(x) = 1 - 2/(exp(2x)+1)
    float e = __expf(2.0f * x);
    return 1.0f - 2.0f * __builtin_amdgcn_rcpf(e + 1.0f);
}

__global__ __launch_bounds__(THREADS, 2) void rnn_scan_kernel(
    const float* __restrict__ input_seq,  // [T,B,4]
    const float* __restrict__ noise,      // [T,B,H]
    const float* __restrict__ J_w,        // [H,H]
    const float* __restrict__ b_in,       // [H,4]
    const float* __restrict__ c_x,        // [H]
    float* __restrict__ states)           // [T,B,H]
{
    const int tid = threadIdx.x;
    const bool act = (tid < HID);
    const int h = act ? tid : (HID - 1);   // clamp idle lanes
    const int b = blockIdx.x;

    // J row h as 50 k-pairs: Jk[j] = {J[h,2j], J[h,2j+1]}. 100 VGPRs.
    v2f Jk[50];
    const float4* Jrow = reinterpret_cast<const float4*>(J_w + (size_t)h * HID);
#pragma unroll
    for (int i = 0; i < 25; ++i) {
        float4 a = Jrow[i];
        Jk[2 * i]     = (v2f){a.x, a.y};
        Jk[2 * i + 1] = (v2f){a.z, a.w};
    }
    // Pin: asm-defined values cannot be rematerialized from the (invariant)
    // global loads -> must stay in registers across the t-loop.
#pragma unroll
    for (int j = 0; j < 50; ++j) asm volatile("" : "+v"(Jk[j]));

    const float4 bin = *reinterpret_cast<const float4*>(b_in + (size_t)h * 4);
    const float cx = c_x[h];

    __shared__ __align__(16) float r_lds[2][HID];

    float x = 0.0f;
    if (act) r_lds[0][h] = 0.0f;  // r(x0) = tanh(0) = 0

    const float* uptr = input_seq + (size_t)b * 4;        // wave-uniform -> s_load
    const float* nptr = noise + (size_t)b * HID + h;
    float4 u  = *reinterpret_cast<const float4*>(uptr);   // t=0
    float  nz = *nptr;

    float* sptr = states + (size_t)b * HID + h;

    __syncthreads();

    for (int t = 0; t < TSTEPS; ++t) {
        // Prefetch t+1 inputs; consumed at end of step -> ~1 step of slack,
        // plus 8 waves/CU of TLP to cover HBM latency.
        const int tn = (t + 1 < TSTEPS) ? (t + 1) : t;
        float4 u_next  = *reinterpret_cast<const float4*>(uptr + (size_t)tn * BATCH * 4);
        float  nz_next = nptr[(size_t)tn * BATCH * HID];

        // x_new[h] = sum_k r[k]*J[h,k], k-packed. r reads are wave-uniform
        // -> LDS broadcast, conflict-free. 4 chains, dep distance 2 instrs.
        const float* rb = &r_lds[t & 1][0];
        v2f a0 = {0.f, 0.f}, a1 = {0.f, 0.f}, a2 = {0.f, 0.f}, a3 = {0.f, 0.f};
#pragma unroll
        for (int i = 0; i < 25; ++i) {
            float4 r4 = *reinterpret_cast<const float4*>(rb + 4 * i);
            v2f r01 = (v2f){r4.x, r4.y};
            v2f r23 = (v2f){r4.z, r4.w};
            if (i & 1) {
                a2 = __builtin_elementwise_fma(Jk[2 * i],     r01, a2);
                a3 = __builtin_elementwise_fma(Jk[2 * i + 1], r23, a3);
            } else {
                a0 = __builtin_elementwise_fma(Jk[2 * i],     r01, a0);
                a1 = __builtin_elementwise_fma(Jk[2 * i + 1], r23, a1);
            }
        }
        v2f av = (a0 + a1) + (a2 + a3);
        float s = av.x + av.y;

        float inp = u.x * bin.x + u.y * bin.y + u.z * bin.z + u.w * bin.w;
        float dx = ALPHA * (-x + s + inp + cx + NSTD * nz);
        x += dx;

        float r = ftanh(x);
        if (act) {
            r_lds[(t + 1) & 1][h] = r;                 // next r first (shortens barrier chain)
            sptr[(size_t)t * BATCH * HID] = x;         // states[t,b,h]
        }

        u = u_next; nz = nz_next;
        __syncthreads();  // 2-wave barrier; other 3 blocks on the CU keep running
    }
}

// Readout: out[b,0] = tanh(states[0,b,:]).wout + wb ; out[b,1] = same at T-1.
__global__ __launch_bounds__(64) void rnn_out_kernel(
    const float* __restrict__ states,
    const float* __restrict__ wout_w,
    const float* __restrict__ wout_b,
    float* __restrict__ out)
{
    const int b = blockIdx.x;
    const int l = threadIdx.x;
    const float* s0 = states + (size_t)b * HID;
    const float* sF = states + ((size_t)(TSTEPS - 1) * BATCH + b) * HID;

    float p0 = 0.f, pF = 0.f;
    if (l < HID) {
        p0 = ftanh(s0[l]) * wout_w[l];
        pF = ftanh(sF[l]) * wout_w[l];
    }
    const int l2 = l + 64;
    if (l2 < HID) {
        p0 += ftanh(s0[l2]) * wout_w[l2];
        pF += ftanh(sF[l2]) * wout_w[l2];
    }
#pragma unroll
    for (int off = 32; off > 0; off >>= 1) {
        p0 += __shfl_xor(p0, off, 64);
        pF += __shfl_xor(pF, off, 64);
    }
    if (l == 0) {
        const float wb = wout_b[0];
        out[b * 2 + 0] = p0 + wb;
        out[b * 2 + 1] = pF + wb;
    }
}

extern "C" void kernel_launch(void* const* d_in, const int* in_sizes, int n_in,
                              void* d_out, int out_size, void* d_ws, size_t ws_size,
                              hipStream_t stream) {
    const float* input_seq = (const float*)d_in[0];
    const float* noise     = (const float*)d_in[1];
    const float* J_w       = (const float*)d_in[2];
    const float* b_in      = (const float*)d_in[3];
    const float* c_x       = (const float*)d_in[4];
    const float* wout_w    = (const float*)d_in[5];
    const float* wout_b    = (const float*)d_in[6];

    float* out    = (float*)d_out;       // [B,2]
    float* states = out + 2 * BATCH;     // [T,B,H]

    rnn_scan_kernel<<<BATCH, THREADS, 0, stream>>>(
        input_seq, noise, J_w, b_in, c_x, states);
    rnn_out_kernel<<<BATCH, 64, 0, stream>>>(states, wout_w, wout_b, out);
}